// Round 16
// baseline (20.238 us; speedup 1.0000x reference)
//
#include <hip/hip_runtime.h>
#include <hip/hip_bf16.h>

// MoE: out[b] = inp[b] @ weight[gate[b]].T
// inp: [4096,512] f32, gate: [4096] int, weight: [32,512,512] f32, out: [4096,512] f32
// Round 16: halve machine-wide phase events. BM=128, 512 threads / 8 waves
// (each 32x32, same per-wave work as r15), BK=128/NKT=4, depth-1 pinned
// prefetch with pre-barrier issue (r15 schedule). Prep cut to 2 barriers via
// per-wave redundant scan. TMAX=2, grid 512. LDS 48KB, VGPR capped <=128.

#define NE     32
#define NBATCH 4096
#define KF     512
#define NF     512
#define BM     128
#define BN     64
#define BK     128
#define NKT    (KF / BK)     // 4
#define TMAX   2             // cnt<=256 (mean 128, sd 11)
#define NCHUNK 64
#define NWG    (8 * NE * TMAX)  // 512, %8==0 -> bijective XCD swizzle

typedef __attribute__((ext_vector_type(8))) short bf16x8;
typedef __attribute__((ext_vector_type(4))) float f32x4;

__device__ __forceinline__ unsigned cvt2(float lo, float hi) {
    __hip_bfloat162 h = __float22bfloat162_rn(make_float2(lo, hi));
    return *reinterpret_cast<unsigned*>(&h);   // v_cvt_pk_bf16_f32
}

// XOR swizzle within [row][128 bf16] (256B row stride); same bijection write+read.
__device__ __forceinline__ int swz(int row, int col_b) {
    return (row * 256 + col_b) ^ ((row & 7) << 4);
}

__global__ __launch_bounds__(512, 2)
void moe_fused(const float* __restrict__ inp,
               const int* __restrict__ gate,
               const float* __restrict__ weight,
               float* __restrict__ out) {
    // bijective XCD-chunk swizzle (512 blocks, 8 XCDs, 64/chunk): XCD k owns
    // experts [4k,4k+4) -> W panels + token rows pinned in that L2.
    const int bid = blockIdx.x;
    const int swb = (bid & 7) * (NWG / 8) + (bid >> 3);
    const int nb    = swb & 7;
    const int y     = swb >> 3;          // 0..63
    const int e     = y >> 1;
    const int local = y & 1;

    // A bf16 [128][128] swizzled @0 (32KB); W bf16 [64][128] @32768 (16KB)
    __shared__ __align__(16) unsigned char lds[(BM + BN) * BK * 2];
    __shared__ int srow[BM];
    __shared__ int chunkinfo[NCHUNK];

    const int tid  = threadIdx.x;
    const int lane = tid & 63;
    const int wid  = tid >> 6;           // 0..7

    // staging map: slot s = i*512+tid -> row = (tid>>5) + 16*i, col4 = (tid&31)*4
    const int srow_i = tid >> 5;
    const int c4     = (tid & 31) * 4;
    const int nblk   = nb * BN;
    const float* wbase = weight + (size_t)e * (NF * KF) + (size_t)nblk * KF;

    float4 ra[8], rw[4];

    // ---- W tile-0 issued BEFORE prep: needs only e; drains under ballots ----
#pragma unroll
    for (int i = 0; i < 4; ++i) {
        int r = srow_i + 16 * i;
        rw[i] = *(const float4*)(wbase + (size_t)r * KF + c4);
    }
    asm volatile("" ::: "memory");       // pin: issue now, don't sink into prep

    // ---- self-prep: ballot-rank tokens of expert e; 2 barriers total ----
    int g[8];
#pragma unroll
    for (int i = 0; i < 8; ++i) g[i] = gate[(wid * 8 + i) * 64 + lane];
#pragma unroll
    for (int i = 0; i < 8; ++i) {
        unsigned long long m = __ballot(g[i] == e);
        if (lane == i) chunkinfo[wid * 8 + i] = __popcll(m);
    }
    if (tid < BM) srow[tid] = -1;
    __syncthreads();                     // barrier 1: counts + srow init visible

    // per-wave redundant scan of all 64 chunk counts (no cross-wave exchange)
    int c = chunkinfo[lane];
    int x = c;
#pragma unroll
    for (int d = 1; d < 64; d <<= 1) {
        int u = __shfl_up(x, d, 64);
        if (lane >= d) x += u;
    }
    const int excl  = x - c;
    const int total = __shfl(x, 63, 64);

    const int m0 = local * BM;
    if (m0 >= total) return;             // block-uniform exit (no barrier pending)

#pragma unroll
    for (int i = 0; i < 8; ++i) {
        unsigned long long m = __ballot(g[i] == e);
        int base = __shfl(excl, wid * 8 + i, 64);   // base of own chunk
        int r = base + __popcll(m & ((1ull << lane) - 1ull));
        if (g[i] == e && r >= m0 && r < m0 + BM)
            srow[r - m0] = (wid * 8 + i) * 64 + lane;
    }
    __syncthreads();                     // barrier 2: srow ready

    const int wm = wid & 3;              // 4 m-quadrants of 32 rows
    const int wn = wid >> 2;             // 2 n-halves of 32 cols

    int arow[8];
    const float* ap[8];
#pragma unroll
    for (int i = 0; i < 8; ++i) {
        arow[i] = srow[srow_i + 16 * i];
        ap[i] = inp + (size_t)(arow[i] < 0 ? 0 : arow[i]) * KF + c4;
    }

#define LOADA(T) do { const int k0 = (T) * BK;                                       \
    _Pragma("unroll") for (int i = 0; i < 8; ++i)                                    \
        ra[i] = (arow[i] >= 0) ? *(const float4*)(ap[i] + k0)                        \
                               : make_float4(0.f, 0.f, 0.f, 0.f); } while (0)

#define LOADW(T) do { const int k0 = (T) * BK;                                       \
    _Pragma("unroll") for (int i = 0; i < 4; ++i) {                                  \
        int r = srow_i + 16 * i;                                                     \
        rw[i] = *(const float4*)(wbase + (size_t)r * KF + k0 + c4); } } while (0)

#define WRITE_TILE() do { const int cb = (tid & 31) * 8;                             \
    _Pragma("unroll") for (int i = 0; i < 8; ++i) {                                  \
        int r = srow_i + 16 * i;                                                     \
        uint2 p = make_uint2(cvt2(ra[i].x, ra[i].y), cvt2(ra[i].z, ra[i].w));        \
        *(uint2*)(lds + swz(r, cb)) = p; }                                           \
    _Pragma("unroll") for (int i = 0; i < 4; ++i) {                                  \
        int r = srow_i + 16 * i;                                                     \
        uint2 p = make_uint2(cvt2(rw[i].x, rw[i].y), cvt2(rw[i].z, rw[i].w));        \
        *(uint2*)(lds + 32768 + swz(r, cb)) = p; } } while (0)

    f32x4 acc[2][2];
#pragma unroll
    for (int mi = 0; mi < 2; ++mi)
#pragma unroll
        for (int ni = 0; ni < 2; ++ni) acc[mi][ni] = (f32x4)(0.f);

#define COMPUTE() do {                                                               \
    _Pragma("unroll") for (int kk = 0; kk < 4; ++kk) {                               \
        const int kb = kk * 64 + 16 * (lane >> 4);                                   \
        bf16x8 af[2], bfr[2];                                                        \
        _Pragma("unroll") for (int mi = 0; mi < 2; ++mi) {                           \
            int r = wm * 32 + mi * 16 + (lane & 15);                                 \
            af[mi] = *(const bf16x8*)(lds + swz(r, kb)); }                           \
        _Pragma("unroll") for (int ni = 0; ni < 2; ++ni) {                           \
            int r = wn * 32 + ni * 16 + (lane & 15);                                 \
            bfr[ni] = *(const bf16x8*)(lds + 32768 + swz(r, kb)); }                  \
        _Pragma("unroll") for (int mi = 0; mi < 2; ++mi)                             \
        _Pragma("unroll") for (int ni = 0; ni < 2; ++ni)                             \
            acc[mi][ni] = __builtin_amdgcn_mfma_f32_16x16x32_bf16(                   \
                af[mi], bfr[ni], acc[mi][ni], 0, 0, 0); } } while (0)

    // ---- K-loop (r15 schedule): loads(t+1) issued before drain+barrier ----
    LOADA(0);                            // W tile 0 in flight since kernel entry
    for (int t = 0; t < NKT; ++t) {
        WRITE_TILE();                    // per-use vmcnt: waits tile-t loads only
        if (t + 1 < NKT) {
            LOADA(t + 1);                // fly across the barrier: +cover
            LOADW(t + 1);
        }
        asm volatile("s_waitcnt lgkmcnt(0)" ::: "memory");
        __builtin_amdgcn_s_barrier();    // LDS tile t consistent (loads in flight)
        asm volatile("" ::: "memory");   // PIN: loads may not sink below
        COMPUTE();
        asm volatile("" ::: "memory");
        __builtin_amdgcn_s_barrier();    // all reads done before next WRITE
        asm volatile("" ::: "memory");
    }
#undef LOADA
#undef LOADW
#undef WRITE_TILE
#undef COMPUTE

    // ---- epilogue: D frag col=lane&15 (n), row=(lane>>4)*4+q (m) ----
#pragma unroll
    for (int mi = 0; mi < 2; ++mi)
#pragma unroll
        for (int q = 0; q < 4; ++q) {
            int m = wm * 32 + mi * 16 + (lane >> 4) * 4 + q;
            int row = srow[m];
            if (row >= 0) {
#pragma unroll
                for (int ni = 0; ni < 2; ++ni)
                    out[(size_t)row * NF + nblk + wn * 32 + ni * 16 + (lane & 15)]
                        = acc[mi][ni][q];
            }
        }
}

extern "C" void kernel_launch(void* const* d_in, const int* in_sizes, int n_in,
                              void* d_out, int out_size, void* d_ws, size_t ws_size,
                              hipStream_t stream) {
    const float* inp    = (const float*)d_in[0];
    const int*   gate   = (const int*)d_in[1];
    const float* weight = (const float*)d_in[2];
    float*       out    = (float*)d_out;

    moe_fused<<<NWG, 512, 0, stream>>>(inp, gate, weight, out);
}

// Round 17
// 18.829 us; speedup vs baseline: 1.0749x; 1.0749x over previous
//
#include <hip/hip_runtime.h>
#include <hip/hip_bf16.h>

// MoE: out[b] = inp[b] @ weight[gate[b]].T
// inp: [4096,512] f32, gate: [4096] int, weight: [32,512,512] f32, out: [4096,512] f32
// Round 17: r15 base (best, 19.06us) + prep critical-path trims:
//  (a) gate loads vectorized int4 (4 loads instead of 16); ballot-rank replaced by
//      16-bit match mask + 4-lane shfl segment scan (thread owns 16 consecutive
//      gates, all inside chunk tid>>2).
//  (b) LOADA drops the zero-fill ternary (clamped row-0 reads; pad outputs never
//      stored -- MFMA row m depends only on A row m; r14-validated).
// Everything else r15-verbatim: BK=128/NKT=4, depth-1 pinned prefetch with
// pre-barrier issue, cvt_pk staging, XOR-swizzle both sides, TMAX=3/grid 768.

#define NE     32
#define NBATCH 4096
#define KF     512
#define NF     512
#define BM     64
#define BN     64
#define BK     128
#define NKT    (KF / BK)     // 4
#define TMAX   3
#define NCHUNK 64
#define NWG    (8 * NE * TMAX)  // 768, %8==0 -> bijective XCD swizzle

typedef __attribute__((ext_vector_type(8))) short bf16x8;
typedef __attribute__((ext_vector_type(4))) float f32x4;

__device__ __forceinline__ unsigned cvt2(float lo, float hi) {
    __hip_bfloat162 h = __float22bfloat162_rn(make_float2(lo, hi));
    return *reinterpret_cast<unsigned*>(&h);   // v_cvt_pk_bf16_f32
}

// XOR swizzle within [row][128 bf16] (256B row stride); same bijection write+read.
__device__ __forceinline__ int swz(int row, int col_b) {
    return (row * 256 + col_b) ^ ((row & 7) << 4);
}

__global__ __launch_bounds__(256)
void moe_fused(const float* __restrict__ inp,
               const int* __restrict__ gate,
               const float* __restrict__ weight,
               float* __restrict__ out) {
    // bijective XCD-chunk swizzle (768 blocks, 8 XCDs, 96/chunk): XCD k owns
    // experts [4k,4k+4) -> W panels + token rows pinned in that L2.
    const int bid = blockIdx.x;
    const int swb = (bid & 7) * (NWG / 8) + (bid >> 3);
    const int nb    = swb & 7;
    const int y     = swb >> 3;          // 0..95
    const int e     = y / 3;
    const int local = y - e * 3;

    __shared__ __align__(16) unsigned char lds[(BM + BN) * BK * 2]; // 32KB single buf
    __shared__ int srow[BM];
    __shared__ int chunkinfo[NCHUNK];
    __shared__ int stotal;

    const int tid  = threadIdx.x;
    const int lane = tid & 63;
    const int wid  = tid >> 6;

    // staging map: slot s = i*256+tid -> row = (tid>>5) + 8*i, col4 = (tid&31)*4
    const int srow_i = tid >> 5;
    const int c4     = (tid & 31) * 4;
    const int nblk   = nb * BN;
    const float* wbase = weight + (size_t)e * (NF * KF) + (size_t)nblk * KF;

    float4 ra[8], rw[8];

    // ---- W tile-0 issued BEFORE prep: only needs e; latency hides under ballots ----
#pragma unroll
    for (int i = 0; i < 8; ++i) {
        int r = srow_i + 8 * i;
        rw[i] = *(const float4*)(wbase + (size_t)r * KF + c4);
    }
    asm volatile("" ::: "memory");       // pin: issue now, don't sink into prep

    // ---- self-prep v2: int4 gate loads + mask/popcount + 4-lane segment scan ----
    // thread owns gates [tid*16, tid*16+16), all inside chunk c = tid>>2
    int4 gv[4];
#pragma unroll
    for (int j = 0; j < 4; ++j)
        gv[j] = ((const int4*)gate)[tid * 4 + j];

    unsigned mask = 0;
#pragma unroll
    for (int j = 0; j < 4; ++j) {
        if (gv[j].x == e) mask |= 1u << (j * 4 + 0);
        if (gv[j].y == e) mask |= 1u << (j * 4 + 1);
        if (gv[j].z == e) mask |= 1u << (j * 4 + 2);
        if (gv[j].w == e) mask |= 1u << (j * 4 + 3);
    }
    const int cnt = __popc(mask);

    // inclusive scan over the 4 threads of this chunk (lanes grouped by 4)
    int xs = cnt;
    {
        int u = __shfl_up(xs, 1, 4); if ((lane & 3) >= 1) xs += u;
        u     = __shfl_up(xs, 2, 4); if ((lane & 3) >= 2) xs += u;
    }
    const int pre = xs - cnt;            // exclusive prefix within chunk
    if ((lane & 3) == 3) chunkinfo[tid >> 2] = xs;   // chunk total
    if (tid < BM) srow[tid] = -1;
    __syncthreads();                     // barrier 1: chunk counts + srow init

    if (tid < NCHUNK) {                  // wave 0: scan 64 chunk counts
        int c = chunkinfo[tid];
        int x = c;
#pragma unroll
        for (int d = 1; d < 64; d <<= 1) {
            int u = __shfl_up(x, d, 64);
            if (lane >= d) x += u;
        }
        chunkinfo[tid] = x - c;          // exclusive chunk base
        if (tid == NCHUNK - 1) stotal = x;
    }
    __syncthreads();                     // barrier 2: bases + total ready

    const int total = stotal;
    const int m0    = local * BM;
    if (m0 >= total) return;             // uniform exit before any raw s_barrier

    // scatter: rank r = chunkbase + within-chunk prefix + intra-thread order
    if (mask) {
        int rr = chunkinfo[tid >> 2] + pre;
        unsigned mm = mask;
        while (mm) {
            int j = __ffs(mm) - 1;
            mm &= mm - 1;
            if (rr >= m0 && rr < m0 + BM)
                srow[rr - m0] = tid * 16 + j;
            ++rr;
        }
    }
    __syncthreads();                     // barrier 3: srow ready

    const int wm = wid & 1;
    const int wn = wid >> 1;

    int arow[8];
    const float* ap[8];
#pragma unroll
    for (int i = 0; i < 8; ++i) {
        arow[i] = srow[srow_i + 8 * i];
        // clamp pad rows to row 0: real data, outputs never stored (r14-validated)
        ap[i] = inp + (size_t)(arow[i] < 0 ? 0 : arow[i]) * KF + c4;
    }

#define LOADA(T) do { const int k0 = (T) * BK;                                       \
    _Pragma("unroll") for (int i = 0; i < 8; ++i)                                    \
        ra[i] = *(const float4*)(ap[i] + k0); } while (0)

#define LOADW(T) do { const int k0 = (T) * BK;                                       \
    _Pragma("unroll") for (int i = 0; i < 8; ++i) {                                  \
        int r = srow_i + 8 * i;                                                      \
        rw[i] = *(const float4*)(wbase + (size_t)r * KF + k0 + c4); } } while (0)

#define WRITE_TILE() do { const int cb = (tid & 31) * 8;                             \
    _Pragma("unroll") for (int i = 0; i < 8; ++i) {                                  \
        int r = srow_i + 8 * i;                                                      \
        uint2 p = make_uint2(cvt2(ra[i].x, ra[i].y), cvt2(ra[i].z, ra[i].w));        \
        *(uint2*)(lds + swz(r, cb)) = p; }                                           \
    _Pragma("unroll") for (int i = 0; i < 8; ++i) {                                  \
        int r = srow_i + 8 * i;                                                      \
        uint2 p = make_uint2(cvt2(rw[i].x, rw[i].y), cvt2(rw[i].z, rw[i].w));        \
        *(uint2*)(lds + 16384 + swz(r, cb)) = p; } } while (0)

    f32x4 acc[2][2];
#pragma unroll
    for (int mi = 0; mi < 2; ++mi)
#pragma unroll
        for (int ni = 0; ni < 2; ++ni) acc[mi][ni] = (f32x4)(0.f);

#define COMPUTE() do {                                                               \
    _Pragma("unroll") for (int kk = 0; kk < 4; ++kk) {                               \
        const int kb = kk * 64 + 16 * (lane >> 4);                                   \
        bf16x8 af[2], bfr[2];                                                        \
        _Pragma("unroll") for (int mi = 0; mi < 2; ++mi) {                           \
            int r = wm * 32 + mi * 16 + (lane & 15);                                 \
            af[mi] = *(const bf16x8*)(lds + swz(r, kb)); }                           \
        _Pragma("unroll") for (int ni = 0; ni < 2; ++ni) {                           \
            int r = wn * 32 + ni * 16 + (lane & 15);                                 \
            bfr[ni] = *(const bf16x8*)(lds + 16384 + swz(r, kb)); }                  \
        _Pragma("unroll") for (int mi = 0; mi < 2; ++mi)                             \
        _Pragma("unroll") for (int ni = 0; ni < 2; ++ni)                             \
            acc[mi][ni] = __builtin_amdgcn_mfma_f32_16x16x32_bf16(                   \
                af[mi], bfr[ni], acc[mi][ni], 0, 0, 0); } } while (0)

    // ---- K-loop (r15 schedule): loads(t+1) issued before drain+barrier ----
    LOADA(0);                            // W tile 0 in flight since kernel entry
    for (int t = 0; t < NKT; ++t) {
        WRITE_TILE();                    // per-use vmcnt: waits tile-t loads only
        if (t + 1 < NKT) {
            LOADA(t + 1);                // fly across the barrier: +cover
            LOADW(t + 1);
        }
        asm volatile("s_waitcnt lgkmcnt(0)" ::: "memory");
        __builtin_amdgcn_s_barrier();    // LDS tile t consistent (loads in flight)
        asm volatile("" ::: "memory");   // PIN: loads may not sink below
        COMPUTE();
        asm volatile("" ::: "memory");
        __builtin_amdgcn_s_barrier();    // all reads done before next WRITE
        asm volatile("" ::: "memory");
    }
#undef LOADA
#undef LOADW
#undef WRITE_TILE
#undef COMPUTE

    // ---- epilogue: D frag col=lane&15 (n), row=(lane>>4)*4+q (m) ----
#pragma unroll
    for (int mi = 0; mi < 2; ++mi)
#pragma unroll
        for (int q = 0; q < 4; ++q) {
            int m = wm * 32 + mi * 16 + (lane >> 4) * 4 + q;
            int row = srow[m];
            if (row >= 0) {
#pragma unroll
                for (int ni = 0; ni < 2; ++ni)
                    out[(size_t)row * NF + nblk + wn * 32 + ni * 16 + (lane & 15)]
                        = acc[mi][ni][q];
            }
        }
}

extern "C" void kernel_launch(void* const* d_in, const int* in_sizes, int n_in,
                              void* d_out, int out_size, void* d_ws, size_t ws_size,
                              hipStream_t stream) {
    const float* inp    = (const float*)d_in[0];
    const int*   gate   = (const int*)d_in[1];
    const float* weight = (const float*)d_in[2];
    float*       out    = (float*)d_out;

    moe_fused<<<NWG, 256, 0, stream>>>(inp, gate, weight, out);
}

// Round 19
// 18.391 us; speedup vs baseline: 1.1004x; 1.0238x over previous
//
#include <hip/hip_runtime.h>
#include <hip/hip_bf16.h>

// MoE: out[b] = inp[b] @ weight[gate[b]].T
// inp: [4096,512] f32, gate: [4096] int, weight: [32,512,512] f32, out: [4096,512] f32
// Round 19: r18 with the scatter bug fixed. r18's failure: __shfl(excl, tid>>2)
// was INSIDE the divergent `if (mask)` -- shfl from an inactive source lane is
// undefined (source active only ~40% of the time) -> garbage chunk bases ->
// scrambled srow. Fix: hoist the shfl out (all lanes active), then branch.
// Retained from r18: 2-barrier prep (per-wave redundant scan), 16B ds_write_b128
// staging. Base r17: BK=128/NKT=4, depth-1 pinned prefetch with pre-barrier
// issue, XOR-swizzle both sides, TMAX=3/grid 768, clamped pad rows.

#define NE     32
#define NBATCH 4096
#define KF     512
#define NF     512
#define BM     64
#define BN     64
#define BK     128
#define NKT    (KF / BK)     // 4
#define TMAX   3
#define NCHUNK 64
#define NWG    (8 * NE * TMAX)  // 768, %8==0 -> bijective XCD swizzle

typedef __attribute__((ext_vector_type(8))) short bf16x8;
typedef __attribute__((ext_vector_type(4))) float f32x4;

__device__ __forceinline__ unsigned cvt2(float lo, float hi) {
    __hip_bfloat162 h = __float22bfloat162_rn(make_float2(lo, hi));
    return *reinterpret_cast<unsigned*>(&h);   // v_cvt_pk_bf16_f32
}

// XOR swizzle within [row][128 bf16] (256B row stride); same bijection write+read.
__device__ __forceinline__ int swz(int row, int col_b) {
    return (row * 256 + col_b) ^ ((row & 7) << 4);
}

__global__ __launch_bounds__(256)
void moe_fused(const float* __restrict__ inp,
               const int* __restrict__ gate,
               const float* __restrict__ weight,
               float* __restrict__ out) {
    // bijective XCD-chunk swizzle (768 blocks, 8 XCDs, 96/chunk): XCD k owns
    // experts [4k,4k+4) -> W panels + token rows pinned in that L2.
    const int bid = blockIdx.x;
    const int swb = (bid & 7) * (NWG / 8) + (bid >> 3);
    const int nb    = swb & 7;
    const int y     = swb >> 3;          // 0..95
    const int e     = y / 3;
    const int local = y - e * 3;

    __shared__ __align__(16) unsigned char lds[(BM + BN) * BK * 2]; // 32KB single buf
    __shared__ int srow[BM];
    __shared__ int chunkinfo[NCHUNK];

    const int tid  = threadIdx.x;
    const int lane = tid & 63;
    const int wid  = tid >> 6;

    // staging map (16B granule): slot s = i*256+tid -> row = (tid>>4) + 16*i,
    // 16B of bf16 (= 2 float4 of source) at float col (tid&15)*8
    const int srow_r = tid >> 4;         // 0..15
    const int c8     = (tid & 15) * 8;   // float offset of first float4
    const int nblk   = nb * BN;
    const float* wbase = weight + (size_t)e * (NF * KF) + (size_t)nblk * KF;

    float4 ra[8], rw[8];                 // [2i],[2i+1] = row-slot i's two float4s

    // ---- W tile-0 issued BEFORE prep: only needs e; latency hides under prep ----
#pragma unroll
    for (int i = 0; i < 4; ++i) {
        int r = srow_r + 16 * i;
        rw[2 * i]     = *(const float4*)(wbase + (size_t)r * KF + c8);
        rw[2 * i + 1] = *(const float4*)(wbase + (size_t)r * KF + c8 + 4);
    }
    asm volatile("" ::: "memory");       // pin: issue now, don't sink into prep

    // ---- self-prep: int4 gate loads + mask rank + per-wave redundant scan ----
    // thread owns gates [tid*16, tid*16+16), all inside chunk tid>>2
    int4 gv[4];
#pragma unroll
    for (int j = 0; j < 4; ++j)
        gv[j] = ((const int4*)gate)[tid * 4 + j];

    unsigned mask = 0;
#pragma unroll
    for (int j = 0; j < 4; ++j) {
        if (gv[j].x == e) mask |= 1u << (j * 4 + 0);
        if (gv[j].y == e) mask |= 1u << (j * 4 + 1);
        if (gv[j].z == e) mask |= 1u << (j * 4 + 2);
        if (gv[j].w == e) mask |= 1u << (j * 4 + 3);
    }
    const int cnt = __popc(mask);

    // inclusive scan over the 4 threads of this chunk (lanes grouped by 4)
    int xs = cnt;
    {
        int u = __shfl_up(xs, 1, 4); if ((lane & 3) >= 1) xs += u;
        u     = __shfl_up(xs, 2, 4); if ((lane & 3) >= 2) xs += u;
    }
    const int pre = xs - cnt;            // exclusive prefix within chunk
    if ((lane & 3) == 3) chunkinfo[tid >> 2] = xs;   // chunk total
    if (tid < BM) srow[tid] = -1;
    __syncthreads();                     // barrier 1: chunk counts + srow init

    // per-wave redundant scan of all 64 chunk counts (no wave-0 serialization)
    int cc = chunkinfo[lane];
    int x  = cc;
#pragma unroll
    for (int d = 1; d < 64; d <<= 1) {
        int u = __shfl_up(x, d, 64);
        if (lane >= d) x += u;
    }
    const int excl  = x - cc;            // lane l holds exclusive base of chunk l
    const int total = __shfl(x, 63, 64);

    // FIX (r18 bug): shfl must run with ALL lanes active -- an inactive source
    // lane yields undefined data. Hoist out of the divergent scatter branch.
    const int chunkbase = __shfl(excl, tid >> 2, 64);

    const int m0 = local * BM;
    if (m0 >= total) return;             // block-uniform exit (no barrier pending)

    // scatter: rank = own-chunk base + within-chunk prefix + intra-thread order
    if (mask) {
        int rr = chunkbase + pre;
        unsigned mm = mask;
        while (mm) {
            int j = __ffs(mm) - 1;
            mm &= mm - 1;
            if (rr >= m0 && rr < m0 + BM)
                srow[rr - m0] = tid * 16 + j;
            ++rr;
        }
    }
    __syncthreads();                     // barrier 2: srow ready

    const int wm = wid & 1;
    const int wn = wid >> 1;

    int arow[4];
    const float* ap[4];
#pragma unroll
    for (int i = 0; i < 4; ++i) {
        arow[i] = srow[srow_r + 16 * i];
        // clamp pad rows to row 0: real data, outputs never stored (r14-validated)
        ap[i] = inp + (size_t)(arow[i] < 0 ? 0 : arow[i]) * KF + c8;
    }

#define LOADA(T) do { const int k0 = (T) * BK;                                       \
    _Pragma("unroll") for (int i = 0; i < 4; ++i) {                                  \
        ra[2 * i]     = *(const float4*)(ap[i] + k0);                                \
        ra[2 * i + 1] = *(const float4*)(ap[i] + k0 + 4); } } while (0)

#define LOADW(T) do { const int k0 = (T) * BK;                                       \
    _Pragma("unroll") for (int i = 0; i < 4; ++i) {                                  \
        int r = srow_r + 16 * i;                                                     \
        rw[2 * i]     = *(const float4*)(wbase + (size_t)r * KF + k0 + c8);          \
        rw[2 * i + 1] = *(const float4*)(wbase + (size_t)r * KF + k0 + c8 + 4); } } while (0)

#define WRITE_TILE() do { const int cb = (tid & 15) * 16;                            \
    _Pragma("unroll") for (int i = 0; i < 4; ++i) {                                  \
        int r = srow_r + 16 * i;                                                     \
        uint4 p = make_uint4(cvt2(ra[2*i].x,   ra[2*i].y),                           \
                             cvt2(ra[2*i].z,   ra[2*i].w),                           \
                             cvt2(ra[2*i+1].x, ra[2*i+1].y),                         \
                             cvt2(ra[2*i+1].z, ra[2*i+1].w));                        \
        *(uint4*)(lds + swz(r, cb)) = p; }                                           \
    _Pragma("unroll") for (int i = 0; i < 4; ++i) {                                  \
        int r = srow_r + 16 * i;                                                     \
        uint4 p = make_uint4(cvt2(rw[2*i].x,   rw[2*i].y),                           \
                             cvt2(rw[2*i].z,   rw[2*i].w),                           \
                             cvt2(rw[2*i+1].x, rw[2*i+1].y),                         \
                             cvt2(rw[2*i+1].z, rw[2*i+1].w));                        \
        *(uint4*)(lds + 16384 + swz(r, cb)) = p; } } while (0)

    f32x4 acc[2][2];
#pragma unroll
    for (int mi = 0; mi < 2; ++mi)
#pragma unroll
        for (int ni = 0; ni < 2; ++ni) acc[mi][ni] = (f32x4)(0.f);

#define COMPUTE() do {                                                               \
    _Pragma("unroll") for (int kk = 0; kk < 4; ++kk) {                               \
        const int kb = kk * 64 + 16 * (lane >> 4);                                   \
        bf16x8 af[2], bfr[2];                                                        \
        _Pragma("unroll") for (int mi = 0; mi < 2; ++mi) {                           \
            int r = wm * 32 + mi * 16 + (lane & 15);                                 \
            af[mi] = *(const bf16x8*)(lds + swz(r, kb)); }                           \
        _Pragma("unroll") for (int ni = 0; ni < 2; ++ni) {                           \
            int r = wn * 32 + ni * 16 + (lane & 15);                                 \
            bfr[ni] = *(const bf16x8*)(lds + 16384 + swz(r, kb)); }                  \
        _Pragma("unroll") for (int mi = 0; mi < 2; ++mi)                             \
        _Pragma("unroll") for (int ni = 0; ni < 2; ++ni)                             \
            acc[mi][ni] = __builtin_amdgcn_mfma_f32_16x16x32_bf16(                   \
                af[mi], bfr[ni], acc[mi][ni], 0, 0, 0); } } while (0)

    // ---- K-loop (r15 schedule): loads(t+1) issued before drain+barrier ----
    LOADA(0);                            // W tile 0 in flight since kernel entry
    for (int t = 0; t < NKT; ++t) {
        WRITE_TILE();                    // per-use vmcnt: waits tile-t loads only
        if (t + 1 < NKT) {
            LOADA(t + 1);                // fly across the barrier: +cover
            LOADW(t + 1);
        }
        asm volatile("s_waitcnt lgkmcnt(0)" ::: "memory");
        __builtin_amdgcn_s_barrier();    // LDS tile t consistent (loads in flight)
        asm volatile("" ::: "memory");   // PIN: loads may not sink below
        COMPUTE();
        asm volatile("" ::: "memory");
        __builtin_amdgcn_s_barrier();    // all reads done before next WRITE
        asm volatile("" ::: "memory");
    }
#undef LOADA
#undef LOADW
#undef WRITE_TILE
#undef COMPUTE

    // ---- epilogue: D frag col=lane&15 (n), row=(lane>>4)*4+q (m) ----
#pragma unroll
    for (int mi = 0; mi < 2; ++mi)
#pragma unroll
        for (int q = 0; q < 4; ++q) {
            int m = wm * 32 + mi * 16 + (lane >> 4) * 4 + q;
            int row = srow[m];
            if (row >= 0) {
#pragma unroll
                for (int ni = 0; ni < 2; ++ni)
                    out[(size_t)row * NF + nblk + wn * 32 + ni * 16 + (lane & 15)]
                        = acc[mi][ni][q];
            }
        }
}

extern "C" void kernel_launch(void* const* d_in, const int* in_sizes, int n_in,
                              void* d_out, int out_size, void* d_ws, size_t ws_size,
                              hipStream_t stream) {
    const float* inp    = (const float*)d_in[0];
    const int*   gate   = (const int*)d_in[1];
    const float* weight = (const float*)d_in[2];
    float*       out    = (float*)d_out;

    moe_fused<<<NWG, 256, 0, stream>>>(inp, gate, weight, out);
}